// Round 10
// baseline (116.458 us; speedup 1.0000x reference)
//
#include <hip/hip_runtime.h>
#include <math.h>

#define NQ   16
#define NB   512
#define NTH  128
#define NREP 4
#define PI_F 3.14159265358979323846f

typedef float2 c32;

__device__ __forceinline__ c32 cmul(c32 a, c32 b) {
    return make_float2(a.x*b.x - a.y*b.y, a.x*b.y + a.y*b.x);
}
__device__ __forceinline__ c32 cfma_(c32 a, c32 b, c32 acc) {
    acc.x = fmaf(a.x, b.x, fmaf(-a.y, b.y, acc.x));
    acc.y = fmaf(a.x, b.y, fmaf( a.y, b.x, acc.y));
    return acc;
}
__device__ __forceinline__ c32 cfmaConjA(c32 a, c32 b, c32 acc) {
    acc.x = fmaf(a.x, b.x, fmaf( a.y, b.y, acc.x));
    acc.y = fmaf(a.x, b.y, fmaf(-a.y, b.x, acc.y));
    return acc;
}
__device__ __forceinline__ c32 cmulConjA(c32 a, c32 b) {
    return cfmaConjA(a, b, make_float2(0.f, 0.f));
}
__device__ __forceinline__ c32 conjc(c32 a){ return make_float2(a.x, -a.y); }
__device__ __forceinline__ c32 cadd(c32 a, c32 b){ return make_float2(a.x+b.x, a.y+b.y); }

// DIAGNOSTIC build: NREP=4 identical repetitions of the full computation so
// the kernel rises above the harness fill dispatches in rocprof (direct
// per-variant timing = dur/4, plus VALUBusy/conflicts/VGPR). Structure =
// round-8 wave-split barrier-free sweep, with stage2 made uniform (2 full
// outputs/lane, no exec-masked Hermitian tail, no divergent mirror writes).

__global__ __launch_bounds__(NTH)
void pqc_mps_kernel(const float* __restrict__ ctx,
                    const float* __restrict__ Wm,
                    const float* __restrict__ bias,
                    const float* __restrict__ params,
                    float* __restrict__ out)
{
    __shared__ c32 Ac[14*272];      // sites 1..14: (q-1)*272 + a*17 + i*8 + r
    __shared__ c32 A0c[16];         // i*8 + r
    __shared__ c32 A15v[32];        // a*2 + i
    __shared__ c32 Renv[15*144];    // R_q: q*144 + m*72 + bl*9 + bp   (wave0)
    __shared__ c32 Ssto[15*144];    // S_q: q*144 + i*72 + bl*9 + bp   (wave1)
    __shared__ c32 TRb[272];        // bb*17 + i*8 + gp                (wave0)
    __shared__ c32 TLT[272];        // (i*8+bp)*17 + a                 (wave1)
    __shared__ c32 Lbuf[144];       // running L env                   (wave1)
    __shared__ c32 Ug[256];         // fused RZ*RY*RX per (l,q)
    __shared__ c32 wv[64];          // w[q,k,i]
    __shared__ float angles[NQ];

    const int b = blockIdx.x;
    const int t = threadIdx.x;
    const int lane = t & 63;

    for (int rep = 0; rep < NREP; ++rep) {
    __syncthreads();

    // ---- phase A: encoding angles (8 lanes per q) ---------------------------
    {
        const int q = t >> 3, g = t & 7;
        const float4* c4 = (const float4*)(ctx + (size_t)b * 256);
        const float4* w4 = (const float4*)(Wm  + (size_t)q * 256);
        float s = 0.f;
        #pragma unroll
        for (int j = 0; j < 8; ++j) {
            const float4 x = c4[g + 8*j], y = w4[g + 8*j];
            s = fmaf(x.x,y.x, fmaf(x.y,y.y, fmaf(x.z,y.z, fmaf(x.w,y.w, s))));
        }
        s += __shfl_xor(s, 4); s += __shfl_xor(s, 2); s += __shfl_xor(s, 1);
        if (g == 0) angles[q] = PI_F * tanhf(s + bias[q]);
    }
    if (t < 64) {  // U = RZ*RY*RX per (l,q) = (t>>4, t&15)
        const float a  = params[t*3 + 0];
        const float bb = params[t*3 + 1];
        const float c  = params[t*3 + 2];
        const float ha = 0.5f*a, hb = 0.5f*bb, hc = 0.5f*c;
        const float ca = cosf(ha), sa = sinf(ha);
        const float cb = cosf(hb), sb = sinf(hb);
        const float cz = cosf(hc), sz = sinf(hc);
        const c32 m00 = make_float2( cb*ca,  sb*sa);
        const c32 m01 = make_float2(-sb*ca, -cb*sa);
        const c32 m10 = make_float2( sb*ca, -cb*sa);
        const c32 m11 = make_float2( cb*ca, -sb*sa);
        const c32 e0 = make_float2(cz, -sz);
        const c32 e1 = make_float2(cz,  sz);
        Ug[t*4 + 0] = cmul(e0, m00);
        Ug[t*4 + 1] = cmul(e0, m01);
        Ug[t*4 + 2] = cmul(e1, m10);
        Ug[t*4 + 3] = cmul(e1, m11);
    }
    __syncthreads();

    if (t < 64) {  // w[q,k,i] = U0q[i^k,:]·(cos h, -i sin h)
        const int q = t >> 2, k = (t>>1)&1, i = t&1;
        const float h = 0.5f * angles[q];
        const float ch = cosf(h), sh = sinf(h);
        const int r0 = (i ^ k) << 1;
        const c32 u0 = Ug[(q<<2) + r0];
        const c32 u1 = Ug[(q<<2) + r0 + 1];
        wv[t] = make_float2(u0.x*ch + u1.y*sh, u0.y*ch - u1.x*sh);
    }
    __syncthreads();

    // ---- phase C: build compact MPS tensors ---------------------------------
    {
        for (int q = 1; q <= 14; ++q) {
            #pragma unroll
            for (int h = 0; h < 2; ++h) {
                const int idx = t + 128*h;
                const int r = idx & 7, i = (idx>>3)&1, a = idx>>4;
                const int m0 = r&1, m1 = (r>>1)&1, m2 = r>>2;
                const int k0 = a&1, k1 = (a>>1)&1, k2 = (a>>2)&1, k3 = a>>3;
                const c32 u3 = Ug[((48+q)<<2) + ((i ^k3)<<1) + m2];
                const c32 u2 = Ug[((32+q)<<2) + ((m2^k2)<<1) + m1];
                const c32 u1 = Ug[((16+q)<<2) + ((m1^k1)<<1) + m0];
                const c32 ww = wv[(q<<2) + (k0<<1) + m0];
                Ac[(q-1)*272 + a*17 + i*8 + r] = cmul(cmul(u3, u2), cmul(u1, ww));
            }
        }
        if (t < 16) {  // site 0
            const int i = t>>3, r = t&7;
            const int m0 = r&1, m1 = (r>>1)&1, m2 = r>>2;
            const c32 u3 = Ug[(48<<2) + (i <<1) + m2];
            const c32 u2 = Ug[(32<<2) + (m2<<1) + m1];
            const c32 u1 = Ug[(16<<2) + (m1<<1) + m0];
            A0c[t] = cmul(cmul(u3, u2), cmul(u1, wv[m0]));
        }
        if (t >= 64 && t < 96) {  // site 15 dense
            const int idx = t - 64, aa = idx >> 1, ii = idx & 1;
            const int K0 = aa&1, K1 = (aa>>1)&1, K2 = (aa>>2)&1, K3 = aa>>3;
            c32 y1[2], y2[2];
            #pragma unroll
            for (int j1 = 0; j1 < 2; ++j1) {
                const int rr = (j1 ^ K1) << 1;
                y1[j1] = cfma_(Ug[((16+15)<<2)+rr], wv[60 + (K0<<1)],
                         cmul (Ug[((16+15)<<2)+rr+1], wv[60 + (K0<<1) + 1]));
            }
            #pragma unroll
            for (int j2 = 0; j2 < 2; ++j2) {
                const int rr = (j2 ^ K2) << 1;
                y2[j2] = cfma_(Ug[((32+15)<<2)+rr], y1[0],
                         cmul (Ug[((32+15)<<2)+rr+1], y1[1]));
            }
            const int rr = (ii ^ K3) << 1;
            A15v[(aa<<1)+ii] = cfma_(Ug[((48+15)<<2)+rr], y2[0],
                               cmul (Ug[((48+15)<<2)+rr+1], y2[1]));
        }
    }
    __syncthreads();

    // uniform stage2 / init decode: lane -> (hi, lo, j), outputs (lo, 2j),(lo, 2j+1)
    const int hiU = lane >> 5;            // m (R) or i (L)
    const int loU = (lane >> 2) & 7;      // bl
    const int jU  = lane & 3;
    const int bpU0 = 2*jU, bpU1 = bpU0 + 1;

    if (t < 64) {
        // ================= wave 0: R chain (no barriers) =====================
        const int bbp = lane>>3, iS = (lane>>2)&1, gpp = lane&3;
        const int bb0 = 2*bbp, bb1 = bb0+1, gq0 = 2*gpp, gq1 = gq0+1;

        {   // init R_14 from A15 (uniform, 2 outputs/lane)
            c32 a0 = make_float2(0.f,0.f), a1 = a0;
            #pragma unroll
            for (int i = 0; i < 2; ++i) {
                const c32 cb_ = A15v[(hiU*8+loU)*2+i];
                a0 = cfmaConjA(cb_, A15v[(hiU*8+bpU0)*2+i], a0);
                a1 = cfmaConjA(cb_, A15v[(hiU*8+bpU1)*2+i], a1);
            }
            Renv[14*144 + hiU*72 + loU*9 + bpU0] = a0;
            Renv[14*144 + hiU*72 + loU*9 + bpU1] = a1;
        }
        for (int s = 1; s <= 14; ++s) {
            const c32* Ap = Ac + (14-s)*272;
            const c32* Rn = Renv + (15-s)*144;
            c32*       Ro = Renv + (14-s)*144;
            // stage1: 2x2 tile -> 4 TR outputs
            c32 aA[8], aB[8], rA[8], rB[8];
            #pragma unroll
            for (int g = 0; g < 8; ++g) {
                aA[g] = Ap[bb0*17 + iS*8 + g];
                aB[g] = Ap[bb1*17 + iS*8 + g];
                rA[g] = Rn[iS*72 + gq0*9 + g];
                rB[g] = Rn[iS*72 + gq1*9 + g];
            }
            c32 t00=make_float2(0.f,0.f), t01=t00, t10=t00, t11=t00;
            #pragma unroll
            for (int g = 0; g < 8; ++g) {
                t00 = cfma_(aA[g], rA[g], t00); t01 = cfma_(aA[g], rB[g], t01);
                t10 = cfma_(aB[g], rA[g], t10); t11 = cfma_(aB[g], rB[g], t11);
            }
            TRb[bb0*17 + iS*8 + gq0] = conjc(t00);
            TRb[bb0*17 + iS*8 + gq1] = conjc(t01);
            TRb[bb1*17 + iS*8 + gq0] = conjc(t10);
            TRb[bb1*17 + iS*8 + gq1] = conjc(t11);
            // stage2 (uniform): R_new[m][bl,bp] = sum_k TR[(m,bl),k] * Ap[(m,bp),k]
            {
                const c32* tr  = TRb + (hiU*8 + loU)*17;
                const c32* ap0 = Ap  + (hiU*8 + bpU0)*17;
                const c32* ap1 = ap0 + 17;
                c32 r0a=make_float2(0.f,0.f), r0b=r0a, r1a=r0a, r1b=r0a;
                #pragma unroll
                for (int k = 0; k < 16; k += 2) {
                    const c32 tA = tr[k], tB = tr[k+1];
                    r0a = cfma_(tA, ap0[k],   r0a);
                    r0b = cfma_(tB, ap0[k+1], r0b);
                    r1a = cfma_(tA, ap1[k],   r1a);
                    r1b = cfma_(tB, ap1[k+1], r1b);
                }
                Ro[hiU*72 + loU*9 + bpU0] = cadd(r0a, r0b);
                Ro[hiU*72 + loU*9 + bpU1] = cadd(r1a, r1b);
            }
        }
    } else {
        // ================= wave 1: L chain (no barriers) =====================
        const int ap_ = lane>>3, iS = (lane>>2)&1, bpp = lane&3;
        const int a0_ = 2*ap_, a1_ = a0_+1, bq0 = 2*bpp, bq1 = bq0+1;
        const int mS = ap_>>2, al0 = a0_&7, al1 = a1_&7;

        {   // init S_0 from A0 (uniform)
            const c32 cb_ = A0c[hiU*8+loU];
            const c32 s0 = cmulConjA(cb_, A0c[hiU*8+bpU0]);
            const c32 s1 = cmulConjA(cb_, A0c[hiU*8+bpU1]);
            Ssto[hiU*72 + loU*9 + bpU0] = s0;
            Ssto[hiU*72 + loU*9 + bpU1] = s1;
            Lbuf[hiU*72 + loU*9 + bpU0] = s0;
            Lbuf[hiU*72 + loU*9 + bpU1] = s1;
        }
        for (int s = 1; s <= 14; ++s) {
            const c32* As = Ac + (s-1)*272;
            c32*       So = Ssto + s*144;
            // stage1: 2x2 tile -> 4 TL outputs (stored transposed)
            c32 lA[8], lB[8], c0v[8], c1v[8];
            #pragma unroll
            for (int g = 0; g < 8; ++g) {
                lA[g]  = Lbuf[mS*72 + al0*9 + g];
                lB[g]  = Lbuf[mS*72 + al1*9 + g];
                c0v[g] = As[(mS*8+g)*17 + iS*8 + bq0];
                c1v[g] = As[(mS*8+g)*17 + iS*8 + bq1];
            }
            c32 t00=make_float2(0.f,0.f), t01=t00, t10=t00, t11=t00;
            #pragma unroll
            for (int g = 0; g < 8; ++g) {
                t00 = cfma_(lA[g], c0v[g], t00); t01 = cfma_(lA[g], c1v[g], t01);
                t10 = cfma_(lB[g], c0v[g], t10); t11 = cfma_(lB[g], c1v[g], t11);
            }
            TLT[(iS*8 + bq0)*17 + a0_] = t00;
            TLT[(iS*8 + bq1)*17 + a0_] = t01;
            TLT[(iS*8 + bq0)*17 + a1_] = t10;
            TLT[(iS*8 + bq1)*17 + a1_] = t11;
            // stage2 (uniform): S[i][bl,bp] = sum_a conj(As[a,i,bl]) * TLT[(i,bp),a]
            {
                const c32* tl0 = TLT + (hiU*8 + bpU0)*17;
                const c32* tl1 = tl0 + 17;
                c32 s0a=make_float2(0.f,0.f), s0b=s0a, s1a=s0a, s1b=s0a;
                #pragma unroll
                for (int k = 0; k < 16; k += 2) {
                    const c32 xA = As[ k   *17 + hiU*8 + loU];
                    const c32 xB = As[(k+1)*17 + hiU*8 + loU];
                    s0a = cfmaConjA(xA, tl0[k],   s0a);
                    s0b = cfmaConjA(xB, tl0[k+1], s0b);
                    s1a = cfmaConjA(xA, tl1[k],   s1a);
                    s1b = cfmaConjA(xB, tl1[k+1], s1b);
                }
                const c32 sv0 = cadd(s0a, s0b);
                const c32 sv1 = cadd(s1a, s1b);
                So[hiU*72 + loU*9 + bpU0] = sv0;
                So[hiU*72 + loU*9 + bpU1] = sv1;
                Lbuf[hiU*72 + loU*9 + bpU0] = sv0;
                Lbuf[hiU*72 + loU*9 + bpU1] = sv1;
            }
        }
    }
    __syncthreads();

    // ---- Z phase: thread (qb, g) handles sites qb and qb+8 ------------------
    {
        const int g = t & 15, qb = t >> 4;   // qb 0..7
        #pragma unroll
        for (int h = 0; h < 2; ++h) {
            const int qq = qb + 8*h;
            float val = 0.f;
            if (qq < 15) {
                const int i = g>>3, blz = g&7;
                const float sign = i ? -1.f : 1.f;
                const c32* Sq = Ssto + qq*144 + i*72 + blz*9;
                const c32* Rq = Renv + qq*144 + i*72 + blz*9;
                #pragma unroll
                for (int j = 0; j < 8; ++j)
                    val += sign * (Sq[j].x*Rq[j].x - Sq[j].y*Rq[j].y);
            } else {
                const int m = g>>3, al = g&7;
                const c32 a0 = A15v[((m*8+al)<<1) + 0];
                const c32 a1 = A15v[((m*8+al)<<1) + 1];
                #pragma unroll
                for (int j = 0; j < 8; ++j) {
                    c32 d = cmulConjA(a0, A15v[((m*8+j)<<1) + 0]);
                    const c32 d1 = cmulConjA(a1, A15v[((m*8+j)<<1) + 1]);
                    d.x -= d1.x; d.y -= d1.y;
                    const c32 Lv = Lbuf[m*72 + al*9 + j];
                    val += Lv.x*d.x - Lv.y*d.y;
                }
            }
            val += __shfl_xor(val, 8);
            val += __shfl_xor(val, 4);
            val += __shfl_xor(val, 2);
            val += __shfl_xor(val, 1);
            if (g == 0) out[b*NQ + qq] = val;
        }
    }
    }  // rep loop
}

extern "C" void kernel_launch(void* const* d_in, const int* in_sizes, int n_in,
                              void* d_out, int out_size, void* d_ws, size_t ws_size,
                              hipStream_t stream) {
    const float* ctx    = (const float*)d_in[0];   // [512,256]
    const float* Wm     = (const float*)d_in[1];   // [16,256]
    const float* bias   = (const float*)d_in[2];   // [16]
    const float* params = (const float*)d_in[3];   // [4,16,3]
    float* out = (float*)d_out;                    // [512,16]
    (void)in_sizes; (void)n_in; (void)out_size; (void)d_ws; (void)ws_size;
    pqc_mps_kernel<<<NB, NTH, 0, stream>>>(ctx, Wm, bias, params, out);
}

// Round 11
// 74.045 us; speedup vs baseline: 1.5728x; 1.5728x over previous
//
#include <hip/hip_runtime.h>
#include <math.h>

#define NQ   16
#define NB   512
#define NTH  128
#define PI_F 3.14159265358979323846f

typedef float2 c32;

__device__ __forceinline__ c32 cmul(c32 a, c32 b) {
    return make_float2(a.x*b.x - a.y*b.y, a.x*b.y + a.y*b.x);
}
__device__ __forceinline__ c32 cfma_(c32 a, c32 b, c32 acc) {
    acc.x = fmaf(a.x, b.x, fmaf(-a.y, b.y, acc.x));
    acc.y = fmaf(a.x, b.y, fmaf( a.y, b.x, acc.y));
    return acc;
}
__device__ __forceinline__ c32 cfmaConjA(c32 a, c32 b, c32 acc) {
    acc.x = fmaf(a.x, b.x, fmaf( a.y, b.y, acc.x));
    acc.y = fmaf(a.x, b.y, fmaf(-a.y, b.x, acc.y));
    return acc;
}
__device__ __forceinline__ c32 cmulConjA(c32 a, c32 b) {
    return cfmaConjA(a, b, make_float2(0.f, 0.f));
}
__device__ __forceinline__ c32 conjc(c32 a){ return make_float2(a.x, -a.y); }
__device__ __forceinline__ c32 cadd(c32 a, c32 b){ return make_float2(a.x+b.x, a.y+b.y); }

// Production build: round-10 structure (wave-split barrier-free sweep,
// uniform stage2, 2 outputs/lane) at NREP=1. Steady-state cost measured at
// 17.5 us/rep (r10: 70.2us / 4 reps, VALUBusy 32%, 1 wave/SIMD).

__global__ __launch_bounds__(NTH)
void pqc_mps_kernel(const float* __restrict__ ctx,
                    const float* __restrict__ Wm,
                    const float* __restrict__ bias,
                    const float* __restrict__ params,
                    float* __restrict__ out)
{
    __shared__ c32 Ac[14*272];      // sites 1..14: (q-1)*272 + a*17 + i*8 + r
    __shared__ c32 A0c[16];         // i*8 + r
    __shared__ c32 A15v[32];        // a*2 + i
    __shared__ c32 Renv[15*144];    // R_q: q*144 + m*72 + bl*9 + bp   (wave0)
    __shared__ c32 Ssto[15*144];    // S_q: q*144 + i*72 + bl*9 + bp   (wave1)
    __shared__ c32 TRb[272];        // bb*17 + i*8 + gp                (wave0)
    __shared__ c32 TLT[272];        // (i*8+bp)*17 + a                 (wave1)
    __shared__ c32 Lbuf[144];       // running L env                   (wave1)
    __shared__ c32 Ug[256];         // fused RZ*RY*RX per (l,q)
    __shared__ c32 wv[64];          // w[q,k,i]
    __shared__ float angles[NQ];

    const int b = blockIdx.x;
    const int t = threadIdx.x;
    const int lane = t & 63;

    // ---- phase A: encoding angles (8 lanes per q) ---------------------------
    {
        const int q = t >> 3, g = t & 7;
        const float4* c4 = (const float4*)(ctx + (size_t)b * 256);
        const float4* w4 = (const float4*)(Wm  + (size_t)q * 256);
        float s = 0.f;
        #pragma unroll
        for (int j = 0; j < 8; ++j) {
            const float4 x = c4[g + 8*j], y = w4[g + 8*j];
            s = fmaf(x.x,y.x, fmaf(x.y,y.y, fmaf(x.z,y.z, fmaf(x.w,y.w, s))));
        }
        s += __shfl_xor(s, 4); s += __shfl_xor(s, 2); s += __shfl_xor(s, 1);
        if (g == 0) angles[q] = PI_F * tanhf(s + bias[q]);
    }
    if (t < 64) {  // U = RZ*RY*RX per (l,q) = (t>>4, t&15)
        const float a  = params[t*3 + 0];
        const float bb = params[t*3 + 1];
        const float c  = params[t*3 + 2];
        const float ha = 0.5f*a, hb = 0.5f*bb, hc = 0.5f*c;
        const float ca = cosf(ha), sa = sinf(ha);
        const float cb = cosf(hb), sb = sinf(hb);
        const float cz = cosf(hc), sz = sinf(hc);
        const c32 m00 = make_float2( cb*ca,  sb*sa);
        const c32 m01 = make_float2(-sb*ca, -cb*sa);
        const c32 m10 = make_float2( sb*ca, -cb*sa);
        const c32 m11 = make_float2( cb*ca, -sb*sa);
        const c32 e0 = make_float2(cz, -sz);
        const c32 e1 = make_float2(cz,  sz);
        Ug[t*4 + 0] = cmul(e0, m00);
        Ug[t*4 + 1] = cmul(e0, m01);
        Ug[t*4 + 2] = cmul(e1, m10);
        Ug[t*4 + 3] = cmul(e1, m11);
    }
    __syncthreads();

    if (t < 64) {  // w[q,k,i] = U0q[i^k,:]·(cos h, -i sin h)
        const int q = t >> 2, k = (t>>1)&1, i = t&1;
        const float h = 0.5f * angles[q];
        const float ch = cosf(h), sh = sinf(h);
        const int r0 = (i ^ k) << 1;
        const c32 u0 = Ug[(q<<2) + r0];
        const c32 u1 = Ug[(q<<2) + r0 + 1];
        wv[t] = make_float2(u0.x*ch + u1.y*sh, u0.y*ch - u1.x*sh);
    }
    __syncthreads();

    // ---- phase C: build compact MPS tensors ---------------------------------
    {
        for (int q = 1; q <= 14; ++q) {
            #pragma unroll
            for (int h = 0; h < 2; ++h) {
                const int idx = t + 128*h;
                const int r = idx & 7, i = (idx>>3)&1, a = idx>>4;
                const int m0 = r&1, m1 = (r>>1)&1, m2 = r>>2;
                const int k0 = a&1, k1 = (a>>1)&1, k2 = (a>>2)&1, k3 = a>>3;
                const c32 u3 = Ug[((48+q)<<2) + ((i ^k3)<<1) + m2];
                const c32 u2 = Ug[((32+q)<<2) + ((m2^k2)<<1) + m1];
                const c32 u1 = Ug[((16+q)<<2) + ((m1^k1)<<1) + m0];
                const c32 ww = wv[(q<<2) + (k0<<1) + m0];
                Ac[(q-1)*272 + a*17 + i*8 + r] = cmul(cmul(u3, u2), cmul(u1, ww));
            }
        }
        if (t < 16) {  // site 0
            const int i = t>>3, r = t&7;
            const int m0 = r&1, m1 = (r>>1)&1, m2 = r>>2;
            const c32 u3 = Ug[(48<<2) + (i <<1) + m2];
            const c32 u2 = Ug[(32<<2) + (m2<<1) + m1];
            const c32 u1 = Ug[(16<<2) + (m1<<1) + m0];
            A0c[t] = cmul(cmul(u3, u2), cmul(u1, wv[m0]));
        }
        if (t >= 64 && t < 96) {  // site 15 dense
            const int idx = t - 64, aa = idx >> 1, ii = idx & 1;
            const int K0 = aa&1, K1 = (aa>>1)&1, K2 = (aa>>2)&1, K3 = aa>>3;
            c32 y1[2], y2[2];
            #pragma unroll
            for (int j1 = 0; j1 < 2; ++j1) {
                const int rr = (j1 ^ K1) << 1;
                y1[j1] = cfma_(Ug[((16+15)<<2)+rr], wv[60 + (K0<<1)],
                         cmul (Ug[((16+15)<<2)+rr+1], wv[60 + (K0<<1) + 1]));
            }
            #pragma unroll
            for (int j2 = 0; j2 < 2; ++j2) {
                const int rr = (j2 ^ K2) << 1;
                y2[j2] = cfma_(Ug[((32+15)<<2)+rr], y1[0],
                         cmul (Ug[((32+15)<<2)+rr+1], y1[1]));
            }
            const int rr = (ii ^ K3) << 1;
            A15v[(aa<<1)+ii] = cfma_(Ug[((48+15)<<2)+rr], y2[0],
                               cmul (Ug[((48+15)<<2)+rr+1], y2[1]));
        }
    }
    __syncthreads();

    // uniform stage2 / init decode: lane -> (hi, lo, j), outputs (lo, 2j),(lo, 2j+1)
    const int hiU = lane >> 5;            // m (R) or i (L)
    const int loU = (lane >> 2) & 7;      // bl
    const int jU  = lane & 3;
    const int bpU0 = 2*jU, bpU1 = bpU0 + 1;

    if (t < 64) {
        // ================= wave 0: R chain (no barriers) =====================
        const int bbp = lane>>3, iS = (lane>>2)&1, gpp = lane&3;
        const int bb0 = 2*bbp, bb1 = bb0+1, gq0 = 2*gpp, gq1 = gq0+1;

        {   // init R_14 from A15 (uniform, 2 outputs/lane)
            c32 a0 = make_float2(0.f,0.f), a1 = a0;
            #pragma unroll
            for (int i = 0; i < 2; ++i) {
                const c32 cb_ = A15v[(hiU*8+loU)*2+i];
                a0 = cfmaConjA(cb_, A15v[(hiU*8+bpU0)*2+i], a0);
                a1 = cfmaConjA(cb_, A15v[(hiU*8+bpU1)*2+i], a1);
            }
            Renv[14*144 + hiU*72 + loU*9 + bpU0] = a0;
            Renv[14*144 + hiU*72 + loU*9 + bpU1] = a1;
        }
        for (int s = 1; s <= 14; ++s) {
            const c32* Ap = Ac + (14-s)*272;
            const c32* Rn = Renv + (15-s)*144;
            c32*       Ro = Renv + (14-s)*144;
            // stage1: 2x2 tile -> 4 TR outputs
            c32 aA[8], aB[8], rA[8], rB[8];
            #pragma unroll
            for (int g = 0; g < 8; ++g) {
                aA[g] = Ap[bb0*17 + iS*8 + g];
                aB[g] = Ap[bb1*17 + iS*8 + g];
                rA[g] = Rn[iS*72 + gq0*9 + g];
                rB[g] = Rn[iS*72 + gq1*9 + g];
            }
            c32 t00=make_float2(0.f,0.f), t01=t00, t10=t00, t11=t00;
            #pragma unroll
            for (int g = 0; g < 8; ++g) {
                t00 = cfma_(aA[g], rA[g], t00); t01 = cfma_(aA[g], rB[g], t01);
                t10 = cfma_(aB[g], rA[g], t10); t11 = cfma_(aB[g], rB[g], t11);
            }
            TRb[bb0*17 + iS*8 + gq0] = conjc(t00);
            TRb[bb0*17 + iS*8 + gq1] = conjc(t01);
            TRb[bb1*17 + iS*8 + gq0] = conjc(t10);
            TRb[bb1*17 + iS*8 + gq1] = conjc(t11);
            // stage2 (uniform): R_new[m][bl,bp] = sum_k TR[(m,bl),k] * Ap[(m,bp),k]
            {
                const c32* tr  = TRb + (hiU*8 + loU)*17;
                const c32* ap0 = Ap  + (hiU*8 + bpU0)*17;
                const c32* ap1 = ap0 + 17;
                c32 r0a=make_float2(0.f,0.f), r0b=r0a, r1a=r0a, r1b=r0a;
                #pragma unroll
                for (int k = 0; k < 16; k += 2) {
                    const c32 tA = tr[k], tB = tr[k+1];
                    r0a = cfma_(tA, ap0[k],   r0a);
                    r0b = cfma_(tB, ap0[k+1], r0b);
                    r1a = cfma_(tA, ap1[k],   r1a);
                    r1b = cfma_(tB, ap1[k+1], r1b);
                }
                Ro[hiU*72 + loU*9 + bpU0] = cadd(r0a, r0b);
                Ro[hiU*72 + loU*9 + bpU1] = cadd(r1a, r1b);
            }
        }
    } else {
        // ================= wave 1: L chain (no barriers) =====================
        const int ap_ = lane>>3, iS = (lane>>2)&1, bpp = lane&3;
        const int a0_ = 2*ap_, a1_ = a0_+1, bq0 = 2*bpp, bq1 = bq0+1;
        const int mS = ap_>>2, al0 = a0_&7, al1 = a1_&7;

        {   // init S_0 from A0 (uniform)
            const c32 cb_ = A0c[hiU*8+loU];
            const c32 s0 = cmulConjA(cb_, A0c[hiU*8+bpU0]);
            const c32 s1 = cmulConjA(cb_, A0c[hiU*8+bpU1]);
            Ssto[hiU*72 + loU*9 + bpU0] = s0;
            Ssto[hiU*72 + loU*9 + bpU1] = s1;
            Lbuf[hiU*72 + loU*9 + bpU0] = s0;
            Lbuf[hiU*72 + loU*9 + bpU1] = s1;
        }
        for (int s = 1; s <= 14; ++s) {
            const c32* As = Ac + (s-1)*272;
            c32*       So = Ssto + s*144;
            // stage1: 2x2 tile -> 4 TL outputs (stored transposed)
            c32 lA[8], lB[8], c0v[8], c1v[8];
            #pragma unroll
            for (int g = 0; g < 8; ++g) {
                lA[g]  = Lbuf[mS*72 + al0*9 + g];
                lB[g]  = Lbuf[mS*72 + al1*9 + g];
                c0v[g] = As[(mS*8+g)*17 + iS*8 + bq0];
                c1v[g] = As[(mS*8+g)*17 + iS*8 + bq1];
            }
            c32 t00=make_float2(0.f,0.f), t01=t00, t10=t00, t11=t00;
            #pragma unroll
            for (int g = 0; g < 8; ++g) {
                t00 = cfma_(lA[g], c0v[g], t00); t01 = cfma_(lA[g], c1v[g], t01);
                t10 = cfma_(lB[g], c0v[g], t10); t11 = cfma_(lB[g], c1v[g], t11);
            }
            TLT[(iS*8 + bq0)*17 + a0_] = t00;
            TLT[(iS*8 + bq1)*17 + a0_] = t01;
            TLT[(iS*8 + bq0)*17 + a1_] = t10;
            TLT[(iS*8 + bq1)*17 + a1_] = t11;
            // stage2 (uniform): S[i][bl,bp] = sum_a conj(As[a,i,bl]) * TLT[(i,bp),a]
            {
                const c32* tl0 = TLT + (hiU*8 + bpU0)*17;
                const c32* tl1 = tl0 + 17;
                c32 s0a=make_float2(0.f,0.f), s0b=s0a, s1a=s0a, s1b=s0a;
                #pragma unroll
                for (int k = 0; k < 16; k += 2) {
                    const c32 xA = As[ k   *17 + hiU*8 + loU];
                    const c32 xB = As[(k+1)*17 + hiU*8 + loU];
                    s0a = cfmaConjA(xA, tl0[k],   s0a);
                    s0b = cfmaConjA(xB, tl0[k+1], s0b);
                    s1a = cfmaConjA(xA, tl1[k],   s1a);
                    s1b = cfmaConjA(xB, tl1[k+1], s1b);
                }
                const c32 sv0 = cadd(s0a, s0b);
                const c32 sv1 = cadd(s1a, s1b);
                So[hiU*72 + loU*9 + bpU0] = sv0;
                So[hiU*72 + loU*9 + bpU1] = sv1;
                Lbuf[hiU*72 + loU*9 + bpU0] = sv0;
                Lbuf[hiU*72 + loU*9 + bpU1] = sv1;
            }
        }
    }
    __syncthreads();

    // ---- Z phase: thread (qb, g) handles sites qb and qb+8 ------------------
    {
        const int g = t & 15, qb = t >> 4;   // qb 0..7
        #pragma unroll
        for (int h = 0; h < 2; ++h) {
            const int qq = qb + 8*h;
            float val = 0.f;
            if (qq < 15) {
                const int i = g>>3, blz = g&7;
                const float sign = i ? -1.f : 1.f;
                const c32* Sq = Ssto + qq*144 + i*72 + blz*9;
                const c32* Rq = Renv + qq*144 + i*72 + blz*9;
                #pragma unroll
                for (int j = 0; j < 8; ++j)
                    val += sign * (Sq[j].x*Rq[j].x - Sq[j].y*Rq[j].y);
            } else {
                const int m = g>>3, al = g&7;
                const c32 a0 = A15v[((m*8+al)<<1) + 0];
                const c32 a1 = A15v[((m*8+al)<<1) + 1];
                #pragma unroll
                for (int j = 0; j < 8; ++j) {
                    c32 d = cmulConjA(a0, A15v[((m*8+j)<<1) + 0]);
                    const c32 d1 = cmulConjA(a1, A15v[((m*8+j)<<1) + 1]);
                    d.x -= d1.x; d.y -= d1.y;
                    const c32 Lv = Lbuf[m*72 + al*9 + j];
                    val += Lv.x*d.x - Lv.y*d.y;
                }
            }
            val += __shfl_xor(val, 8);
            val += __shfl_xor(val, 4);
            val += __shfl_xor(val, 2);
            val += __shfl_xor(val, 1);
            if (g == 0) out[b*NQ + qq] = val;
        }
    }
}

extern "C" void kernel_launch(void* const* d_in, const int* in_sizes, int n_in,
                              void* d_out, int out_size, void* d_ws, size_t ws_size,
                              hipStream_t stream) {
    const float* ctx    = (const float*)d_in[0];   // [512,256]
    const float* Wm     = (const float*)d_in[1];   // [16,256]
    const float* bias   = (const float*)d_in[2];   // [16]
    const float* params = (const float*)d_in[3];   // [4,16,3]
    float* out = (float*)d_out;                    // [512,16]
    (void)in_sizes; (void)n_in; (void)out_size; (void)d_ws; (void)ws_size;
    pqc_mps_kernel<<<NB, NTH, 0, stream>>>(ctx, Wm, bias, params, out);
}